// Round 10
// baseline (1520.058 us; speedup 1.0000x reference)
//
#include <hip/hip_runtime.h>

// MLPDecoder_Causal: B=8,N=32,T=32,D=4,K=2,H=256,P=4,E=992.
// R15: barrier-free wave-independent step kernel.
// Ladder law (R7-R14): every multi-wave barrier-phased block = 155-270us/step
// with ALL pipes idle (R14: VALU 16%, MFMA 2.5%, occ 11.5%, traffic clean).
// R6 (80% VALU busy) proves long unbroken per-thread streams hide latency.
// This round: wave = one (bt,n); grid 2048 x 64thr; NO cross-wave coupling.
//  - A-frag lane mapping is a bijection -> each lane computes ITS OWN 128 h1
//    values on VALU straight into Af regs (64 VGPR). No LDS staging, no barrier.
//  - layer2: 512 MFMA/wave over 4 col-quarters (acc 32 VGPR at a time).
//  - epilogue/hooks/agg math identical to R14 (absmax 0.03125 verified).
//  - tail output-MLP per wave via 3KB LDS; intra-wave __syncthreads ~free.
//  - no launch_bounds pressure: 8 waves/CU scheduled (2/SIMD) -> VGPR budget
//    256, compiler free to batch loads without spilling (R13 lesson).
typedef unsigned short u16;
typedef unsigned int   u32;
typedef unsigned long long u64;
typedef __attribute__((ext_vector_type(8))) _Float16 f16x8;
typedef __attribute__((ext_vector_type(4))) float f32x4;

__device__ __forceinline__ float bf2f(u16 s){ u32 u = ((u32)s)<<16; float f; __builtin_memcpy(&f,&u,4); return f; }
__device__ __forceinline__ u16 f2h(float f){ _Float16 h = (_Float16)f; return __builtin_bit_cast(u16, h); }
// generic input accessor (prep only): F=1 -> memory is bf16, F=0 -> fp32
__device__ __forceinline__ float inV(const void* p, int i, int F){
  return F ? bf2f(((const u16*)p)[i]) : ((const float*)p)[i];
}

// wave0 scans first 512 u16 of `inputs`: bf16 N(0,1) data never has exponent
// field >= 0xA0; fp32 low-halves hit that ~37% of the time.
__device__ __forceinline__ void detect_bf16(const void* inputs0, int tid, int* flagL){
  if (tid < 64){
    const uint4* dp = (const uint4*)inputs0;
    uint4 v = dp[tid];
    u32 wds[4] = {v.x, v.y, v.z, v.w};
    int sus = 0;
#pragma unroll
    for (int i2=0; i2<4; ++i2){
      u32 wv = wds[i2];
      u32 h0 = wv & 0xffffu, h1 = wv >> 16;
      if (((h0>>7)&0xffu) >= 0xA0u) sus = 1;
      if (((h1>>7)&0xffu) >= 0xA0u) sus = 1;
    }
    u64 bal = __ballot(sus);
    if (tid == 0) *flagL = (bal == 0ull) ? 1 : 0;
  }
}

// ---------------- workspace layout (bytes) ----------------
#define WS_LAST0 0
#define WS_LAST1 32768
#define WS_WF    65536        // fp32 misc, 8648 floats
#define WS_W2P   102400       // W2 fp16 fragment pack, 131072 u16 = 256KB
#define WS_WO1T  364544       // Wo1^T fp16 [256][264], 135168 B
#define WS_WO2T  499712       // Wo2^T fp16 [256][256], 131072 B

// wf offsets (floats)
#define WF_W1   0             // [k][kd][c]  2*8*256
#define WF_B1   4096          // 2*256
#define WF_B2   4608          // 2*256
#define WF_WO3  5120          // [i][d] 256*4
#define WF_BO1  6144          // 256
#define WF_BO2  6400          // 256
#define WF_BO3  6656          // 4 (+4 pad)
#define WF_EV   6664          // [e][k] 992*2 softmax probs

// prep flat-work partition
#define PR_MISC 6660
#define PR_EV   (PR_MISC + 992)      // 7652
#define PR_L0   (PR_EV + 8192)      // 15844
#define PR_RO   (PR_L0 + 15872)     // 31716
#define PR_W2P  (PR_RO + 131072)    // 162788
#define PR_WO1T (PR_W2P + 67584)    // 230372
#define PR_WO2T (PR_WO1T + 65536)   // 295908

// ---------------- prep: dtype-resolve + pack everything once ----------------
__global__ void k_prep(const void* __restrict__ inputs, const void* __restrict__ rel_graph,
                       const void* __restrict__ gumbel,
                       const void* __restrict__ W1, const void* __restrict__ b1,
                       const void* __restrict__ W2, const void* __restrict__ b2,
                       const void* __restrict__ Wo1, const void* __restrict__ bo1,
                       const void* __restrict__ Wo2, const void* __restrict__ bo2,
                       const void* __restrict__ Wo3, const void* __restrict__ bo3,
                       float* __restrict__ wf, u16* __restrict__ w2p,
                       u16* __restrict__ wo1t, u16* __restrict__ wo2t,
                       float* __restrict__ last0, float* __restrict__ out)
{
  __shared__ int flagL;
  int tid = threadIdx.x;
  detect_bf16(inputs, tid, &flagL);
  __syncthreads();
  const int F = flagL;
  int i = blockIdx.x*256 + tid;
  if (i < PR_MISC){                    // fp32 cache, flat index == wf index
    const void* src; int off;
    if      (i < 4096) { src = W1;  off = i; }
    else if (i < 4608) { src = b1;  off = i-4096; }
    else if (i < 5120) { src = b2;  off = i-4608; }
    else if (i < 6144) { src = Wo3; off = i-5120; }
    else if (i < 6400) { src = bo1; off = i-6144; }
    else if (i < 6656) { src = bo2; off = i-6400; }
    else               { src = bo3; off = i-6656; }
    wf[i] = inV(src, off, F);
    return;
  }
  if (i < PR_EV){                      // softmax((rel+gumbel)/0.5), K=2
    int e = i - PR_MISC;
    float l0 = (inV(rel_graph,2*e,F)   + inV(gumbel,2*e,F))   * 2.f;
    float l1 = (inV(rel_graph,2*e+1,F) + inV(gumbel,2*e+1,F)) * 2.f;
    float m = fmaxf(l0,l1);
    float e0 = __expf(l0-m), e1 = __expf(l1-m), s = 1.f/(e0+e1);
    wf[WF_EV+2*e]   = e0*s;
    wf[WF_EV+2*e+1] = e1*s;
    return;
  }
  if (i < PR_L0){                      // last0[bt][n][d] = inputs[b, n, 4*tp, d]
    int j = i - PR_EV;
    int d = j&3, nn = (j>>2)&31, bt = j>>7, b = bt>>3, tp = bt&7;
    last0[j] = inV(inputs, b*4096 + nn*128 + tp*16 + d, F);
    return;
  }
  if (i < PR_RO){                      // rel_out broadcast
    int j = i - PR_L0;
    out[31744 + j] = inV(rel_graph, j % 1984, F);
    return;
  }
  if (i < PR_W2P){                     // W2 -> fp16 fragment pack
    // flat: (((k*16 + t)*8 + q)*64 + l)*8 + ei
    int e = i - PR_RO;
    int ei = e & 7, l = (e>>3)&63, q = (e>>9)&7, t = (e>>12)&15, k = e>>16;
    int kk  = q*32 + (l>>4)*8 + ei;    // contraction index (h1 col)
    int col = t*16 + (l&15);           // output col
    w2p[e] = f2h(inV(W2, k*65536 + kk*256 + col, F));
    return;
  }
  if (i < PR_WO1T){                    // Wo1^T fp16 [c][264], pad i>=260 -> 0
    int e = i - PR_W2P;
    int c = e / 264, ii = e - c*264;
    wo1t[e] = (ii < 260) ? f2h(inV(Wo1, ii*256 + c, F)) : (u16)0;
    return;
  }
  if (i < PR_WO2T){                    // Wo2^T fp16 [c][256]
    int e = i - PR_WO1T;
    int c = e >> 8, ii = e & 255;
    wo2t[e] = f2h(inV(Wo2, ii*256 + c, F));
  }
}

// ---------------- k_step: one WAVE per (bt,n), barrier-free ----------------
// LDS float offsets (single wave): aug[268] | o1[256] | o2[256] = 3120 B
#define SA_AUG 0
#define SA_O1  268
#define SA_O2  524
#define SA_TOT 780

__global__ __launch_bounds__(64) void k_step(
    const float* __restrict__ lastIn, float* __restrict__ lastOut,
    const float* __restrict__ wf, const u16* __restrict__ w2p,
    const u16* __restrict__ wo1t, const u16* __restrict__ wo2t,
    float* __restrict__ hooks, float* __restrict__ out0, int pstep)
{
  __shared__ __align__(16) float sm[SA_TOT];

  const int l = threadIdx.x;             // lane 0..63
  const int n = blockIdx.x & 31, bt = blockIdx.x >> 5;
  const int b = bt>>3, tp = bt&7;
  const int l15 = l & 15, lg = l >> 4;
  const int hb = (((pstep*8 + tp)*8 + b)*992 + n*31)*256;

  // ---- per-lane x rows j0=l15 (always live), j1=16+l15 (31 = pad -> 0)
  float x0[8], x1[8];
  {
    const int j0 = l15, j1 = 16 + l15;
    int s0i = j0 + (j0 >= n);
    float4 sv = *(const float4*)&lastIn[bt*128 + s0i*4];
    float4 rv = *(const float4*)&lastIn[bt*128 + n*4];
    x0[0]=sv.x; x0[1]=sv.y; x0[2]=sv.z; x0[3]=sv.w;
    x0[4]=rv.x; x0[5]=rv.y; x0[6]=rv.z; x0[7]=rv.w;
    if (j1 < 31){
      int s1i = j1 + (j1 >= n);
      float4 sw = *(const float4*)&lastIn[bt*128 + s1i*4];
      x1[0]=sw.x; x1[1]=sw.y; x1[2]=sw.z; x1[3]=sw.w;
      x1[4]=rv.x; x1[5]=rv.y; x1[6]=rv.z; x1[7]=rv.w;
    } else {
#pragma unroll
      for (int i2=0;i2<8;++i2) x1[i2]=0.f;
    }
  }

  float agg[16];
#pragma unroll
  for (int t=0;t<16;++t) agg[t]=0.f;

  for (int k=0;k<2;++k){
    // ---- layer1 fp32 VALU, straight into A-frag regs (bijective mapping):
    // Af{0,1}[q][i] = h1[{l15, 16+l15}][q*32 + lg*8 + i]
    uint4 Af0[8], Af1[8];
#pragma unroll
    for (int q=0;q<8;++q){
      const int cb = q*32 + lg*8;
      const float* W1k = wf + WF_W1 + k*2048;
      float a0[8], a1[8];
      {
        float4 ba = *(const float4*)&wf[WF_B1 + k*256 + cb];
        float4 bb = *(const float4*)&wf[WF_B1 + k*256 + cb + 4];
        a0[0]=ba.x; a0[1]=ba.y; a0[2]=ba.z; a0[3]=ba.w;
        a0[4]=bb.x; a0[5]=bb.y; a0[6]=bb.z; a0[7]=bb.w;
#pragma unroll
        for (int i2=0;i2<8;++i2) a1[i2]=a0[i2];
      }
#pragma unroll
      for (int kd=0;kd<8;++kd){
        float4 wa = *(const float4*)&W1k[kd*256 + cb];
        float4 wb = *(const float4*)&W1k[kd*256 + cb + 4];
        float v0 = x0[kd], v1 = x1[kd];
        a0[0]+=v0*wa.x; a0[1]+=v0*wa.y; a0[2]+=v0*wa.z; a0[3]+=v0*wa.w;
        a0[4]+=v0*wb.x; a0[5]+=v0*wb.y; a0[6]+=v0*wb.z; a0[7]+=v0*wb.w;
        a1[0]+=v1*wa.x; a1[1]+=v1*wa.y; a1[2]+=v1*wa.z; a1[3]+=v1*wa.w;
        a1[4]+=v1*wb.x; a1[5]+=v1*wb.y; a1[6]+=v1*wb.z; a1[7]+=v1*wb.w;
      }
      f16x8 h0, h1v;
#pragma unroll
      for (int i2=0;i2<8;++i2){
        h0[i2]  = (_Float16)fmaxf(a0[i2],0.f);
        h1v[i2] = (_Float16)fmaxf(a1[i2],0.f);
      }
      Af0[q] = __builtin_bit_cast(uint4, h0);
      Af1[q] = __builtin_bit_cast(uint4, h1v);
    }

    // ---- edge softmax probs for this lane's 8 D-rows (j==31 -> ev=0 masks pad)
    float evr[8];
#pragma unroll
    for (int rt=0;rt<2;++rt)
#pragma unroll
      for (int rr=0;rr<4;++rr){
        int j = rt*16 + lg*4 + rr;
        evr[rt*4+rr] = (j < 31) ? wf[WF_EV + 2*(n*31+j) + k] : 0.f;
      }

    // ---- layer2 MFMA over 4 column quarters; epilogue per quarter
#pragma unroll
    for (int cq=0;cq<4;++cq){
      f32x4 acc0[4], acc1[4];          // rows 0-15 / 16-31
#pragma unroll
      for (int nt=0;nt<4;++nt){
        float bv = wf[WF_B2 + k*256 + cq*64 + nt*16 + l15];
        f32x4 bi = {bv,bv,bv,bv};
        acc0[nt]=bi; acc1[nt]=bi;
      }
#pragma unroll
      for (int q=0;q<8;++q){
#pragma unroll
        for (int nt=0;nt<4;++nt){
          f16x8 Bf = __builtin_bit_cast(f16x8,
              *(const uint4*)(w2p + (((k*16 + cq*4 + nt)*8 + q)<<9) + (l<<3)));
          acc0[nt] = __builtin_amdgcn_mfma_f32_16x16x32_f16(
              __builtin_bit_cast(f16x8, Af0[q]), Bf, acc0[nt], 0,0,0);
          acc1[nt] = __builtin_amdgcn_mfma_f32_16x16x32_f16(
              __builtin_bit_cast(f16x8, Af1[q]), Bf, acc1[nt], 0,0,0);
        }
      }
      // D layout: row = rt*16 + lg*4 + rr, col = cq*64 + nt*16 + l15
#pragma unroll
      for (int rt=0;rt<2;++rt)
#pragma unroll
        for (int rr=0;rr<4;++rr){
          int j = rt*16 + lg*4 + rr;
          float ev = evr[rt*4+rr];
#pragma unroll
          for (int nt=0;nt<4;++nt){
            float v = rt ? acc1[nt][rr] : acc0[nt][rr];
            float m = fmaxf(v, 0.f)*ev;
            agg[cq*4+nt] += m;
            if (k == 1 && j < 31)
              hooks[hb + j*256 + cq*64 + nt*16 + l15] = m;
          }
        }
    }
  }

  // ---- column aggregate: butterfly over the 4 lane-groups
#pragma unroll
  for (int t=0;t<16;++t){
    agg[t] += __shfl_xor(agg[t], 16);
    agg[t] += __shfl_xor(agg[t], 32);
  }
  if (lg == 0){
#pragma unroll
    for (int t=0;t<16;++t)
      sm[SA_AUG + 4 + (t>>2)*64 + (t&3)*16 + l15] = agg[t];
  }
  if (l < 4)      sm[SA_AUG + l] = lastIn[bt*128 + n*4 + l];
  else if (l < 8) sm[SA_AUG + 260 + (l-4)] = 0.f;
  __syncthreads();                     // intra-wave: ~free

  // ---- o1 = relu(aug @ Wo1 + bo1): 4 cols per lane
  {
    const int c0 = l << 2;
    float s0 = wf[WF_BO1+c0], s1 = wf[WF_BO1+c0+1],
          s2 = wf[WF_BO1+c0+2], s3 = wf[WF_BO1+c0+3];
#pragma unroll 3
    for (int i=0;i<33;++i){
      float4 xa = *(const float4*)&sm[SA_AUG + i*8];
      float4 xb = *(const float4*)&sm[SA_AUG + i*8 + 4];
      f16x8 w0 = __builtin_bit_cast(f16x8, *(const uint4*)(wo1t + (c0+0)*264 + i*8));
      f16x8 w1 = __builtin_bit_cast(f16x8, *(const uint4*)(wo1t + (c0+1)*264 + i*8));
      f16x8 w2 = __builtin_bit_cast(f16x8, *(const uint4*)(wo1t + (c0+2)*264 + i*8));
      f16x8 w3 = __builtin_bit_cast(f16x8, *(const uint4*)(wo1t + (c0+3)*264 + i*8));
      s0 += xa.x*(float)w0[0] + xa.y*(float)w0[1] + xa.z*(float)w0[2] + xa.w*(float)w0[3]
          + xb.x*(float)w0[4] + xb.y*(float)w0[5] + xb.z*(float)w0[6] + xb.w*(float)w0[7];
      s1 += xa.x*(float)w1[0] + xa.y*(float)w1[1] + xa.z*(float)w1[2] + xa.w*(float)w1[3]
          + xb.x*(float)w1[4] + xb.y*(float)w1[5] + xb.z*(float)w1[6] + xb.w*(float)w1[7];
      s2 += xa.x*(float)w2[0] + xa.y*(float)w2[1] + xa.z*(float)w2[2] + xa.w*(float)w2[3]
          + xb.x*(float)w2[4] + xb.y*(float)w2[5] + xb.z*(float)w2[6] + xb.w*(float)w2[7];
      s3 += xa.x*(float)w3[0] + xa.y*(float)w3[1] + xa.z*(float)w3[2] + xa.w*(float)w3[3]
          + xb.x*(float)w3[4] + xb.y*(float)w3[5] + xb.z*(float)w3[6] + xb.w*(float)w3[7];
    }
    __syncthreads();
    *(float4*)&sm[SA_O1 + c0] =
        make_float4(fmaxf(s0,0.f), fmaxf(s1,0.f), fmaxf(s2,0.f), fmaxf(s3,0.f));
  }
  __syncthreads();

  // ---- o2 = relu(o1 @ Wo2 + bo2): 4 cols per lane
  {
    const int c0 = l << 2;
    float s0 = wf[WF_BO2+c0], s1 = wf[WF_BO2+c0+1],
          s2 = wf[WF_BO2+c0+2], s3 = wf[WF_BO2+c0+3];
#pragma unroll 4
    for (int i=0;i<32;++i){
      float4 xa = *(const float4*)&sm[SA_O1 + i*8];
      float4 xb = *(const float4*)&sm[SA_O1 + i*8 + 4];
      f16x8 w0 = __builtin_bit_cast(f16x8, *(const uint4*)(wo2t + (c0+0)*256 + i*8));
      f16x8 w1 = __builtin_bit_cast(f16x8, *(const uint4*)(wo2t + (c0+1)*256 + i*8));
      f16x8 w2 = __builtin_bit_cast(f16x8, *(const uint4*)(wo2t + (c0+2)*256 + i*8));
      f16x8 w3 = __builtin_bit_cast(f16x8, *(const uint4*)(wo2t + (c0+3)*256 + i*8));
      s0 += xa.x*(float)w0[0] + xa.y*(float)w0[1] + xa.z*(float)w0[2] + xa.w*(float)w0[3]
          + xb.x*(float)w0[4] + xb.y*(float)w0[5] + xb.z*(float)w0[6] + xb.w*(float)w0[7];
      s1 += xa.x*(float)w1[0] + xa.y*(float)w1[1] + xa.z*(float)w1[2] + xa.w*(float)w1[3]
          + xb.x*(float)w1[4] + xb.y*(float)w1[5] + xb.z*(float)w1[6] + xb.w*(float)w1[7];
      s2 += xa.x*(float)w2[0] + xa.y*(float)w2[1] + xa.z*(float)w2[2] + xa.w*(float)w2[3]
          + xb.x*(float)w2[4] + xb.y*(float)w2[5] + xb.z*(float)w2[6] + xb.w*(float)w2[7];
      s3 += xa.x*(float)w3[0] + xa.y*(float)w3[1] + xa.z*(float)w3[2] + xa.w*(float)w3[3]
          + xb.x*(float)w3[4] + xb.y*(float)w3[5] + xb.z*(float)w3[6] + xb.w*(float)w3[7];
    }
    __syncthreads();
    *(float4*)&sm[SA_O2 + c0] =
        make_float4(fmaxf(s0,0.f), fmaxf(s1,0.f), fmaxf(s2,0.f), fmaxf(s3,0.f));
  }
  __syncthreads();

  // ---- p = o2 @ Wo3 + bo3; residual; store
  {
    int d = l & 3, ch = l >> 2;          // 16 chunks x 16 elems
    float p = 0.f;
#pragma unroll
    for (int ii=0; ii<16; ++ii){
      int i = ch*16 + ii;
      p += sm[SA_O2 + i]*wf[WF_WO3 + i*4 + d];
    }
#pragma unroll
    for (int s2=4; s2<64; s2<<=1) p += __shfl_xor(p, s2);
    if (ch == 0){
      float lv = lastIn[bt*128 + n*4 + d] + p + wf[WF_BO3 + d];
      lastOut[bt*128 + n*4 + d] = lv;
      int t = tp*4 + pstep;
      if (t < 31) out0[b*3968 + n*124 + t*4 + d] = lv;
    }
  }
}

extern "C" void kernel_launch(void* const* d_in, const int* in_sizes, int n_in,
                              void* d_out, int out_size, void* d_ws, size_t ws_size,
                              hipStream_t stream) {
  const void* inputs    = d_in[0];
  const void* rel_graph = d_in[1];
  const void* W1  = d_in[2];
  const void* b1  = d_in[3];
  const void* W2  = d_in[4];
  const void* b2  = d_in[5];
  const void* Wo1 = d_in[6];
  const void* bo1 = d_in[7];
  const void* Wo2 = d_in[8];
  const void* bo2 = d_in[9];
  const void* Wo3 = d_in[10];
  const void* bo3 = d_in[11];
  const void* gumbel = d_in[14];
  float* out = (float*)d_out;
  char* ws = (char*)d_ws;
  float* L0   = (float*)(ws + WS_LAST0);
  float* L1   = (float*)(ws + WS_LAST1);
  float* wf   = (float*)(ws + WS_WF);
  u16*   w2p  = (u16*)  (ws + WS_W2P);
  u16*   wo1t = (u16*)  (ws + WS_WO1T);
  u16*   wo2t = (u16*)  (ws + WS_WO2T);

  k_prep<<<(PR_WO2T + 255)/256, 256, 0, stream>>>(
      inputs, rel_graph, gumbel, W1, b1, W2, b2, Wo1, bo1, Wo2, bo2, Wo3, bo3,
      wf, w2p, wo1t, wo2t, L0, out);
  for (int p = 0; p < 4; ++p) {
    const float* lin  = (p & 1) ? L1 : L0;
    float*       lout = (p & 1) ? L0 : L1;
    k_step<<<2048, 64, 0, stream>>>(lin, lout, wf, w2p, wo1t, wo2t,
                                    out + 47616, out, p);
  }
}